// Round 14
// baseline (142.802 us; speedup 1.0000x reference)
//
#include <hip/hip_runtime.h>
#include <hip/hip_bf16.h>
#include <cstdint>

// ---------------- problem constants ----------------
#define BB 1024          // batch
#define DD 512           // dim
#define CC 50000         // classes
#define CCP 50048        // padded classes (1564 * 32)
#define NCT 1564         // col-tiles of 32
#define NBLK 1024        // 8 m-tiles * 128 splits (XCD-divisible)
#define SCALE_F 64.0f
#define LOG2E_F 1.44269504088896340736f
#define SCALE_L2E_F (SCALE_F * LOG2E_F)      // 92.3324826...
#define COS_M_F 0.87758256189037276f
#define SIN_M_F 0.47942553860420301f
#define TH_F   (-0.87758256189037276f)
#define MM_F   0.23971276930210156f

typedef __attribute__((ext_vector_type(4))) int i32x4;
typedef __attribute__((ext_vector_type(8))) char char8;

// ---------------- ws layout (bytes) ----------------
#define OFF_RS   ((size_t)0)                          // [1024] float row sum-exp accum
#define OFF_ES   (OFF_RS + 4096)                      // [1024] float (e scales)
#define OFF_WS   (OFF_ES + 4096)                      // [50048] float (w scales, padded)
#define OFF_EI8  (OFF_WS + 204800)                    // [1024][512] i8
#define OFF_WI8  (OFF_EI8 + (size_t)BB*DD)            // [50048][512] i8 (padded)

// ---------------- kernel 1: fused normalize+quantize + init -------------------
__global__ void quant_kernel(const float* __restrict__ emb, const float* __restrict__ wgt,
                             char* __restrict__ ei8, float* __restrict__ es,
                             char* __restrict__ wi8, float* __restrict__ wsc,
                             float* __restrict__ rowsum, float* __restrict__ out) {
    const int blk = blockIdx.x;
    if (blk == 12756) {
        const int t = threadIdx.x;   // 256
        #pragma unroll
        for (int i = 0; i < 4; ++i) rowsum[i * 256 + t] = 0.f;
        if (t == 0) out[0] = 0.f;
        // zero pad rows 50000..50047 (24576 B): 96 B per thread
        int4* pz = reinterpret_cast<int4*>(wi8 + (size_t)CC * DD + t * 96);
        #pragma unroll
        for (int i = 0; i < 6; ++i) pz[i] = (int4){0, 0, 0, 0};
        if (t < CCP - CC) wsc[CC + t] = 0.f;
        return;
    }
    const int r4 = threadIdx.x >> 6;
    const int l  = threadIdx.x & 63;
    const bool isw = blk < 12500;
    const int row = isw ? (blk * 4 + r4) : ((blk - 12500) * 4 + r4);
    const float* src = (isw ? wgt : emb) + (size_t)row * DD;
    const float4* r = reinterpret_cast<const float4*>(src);
    float4 v0 = r[l * 2 + 0];
    float4 v1 = r[l * 2 + 1];
    float ss = v0.x*v0.x + v0.y*v0.y + v0.z*v0.z + v0.w*v0.w
             + v1.x*v1.x + v1.y*v1.y + v1.z*v1.z + v1.w*v1.w;
    float mx = fmaxf(fmaxf(fmaxf(fabsf(v0.x), fabsf(v0.y)), fmaxf(fabsf(v0.z), fabsf(v0.w))),
                     fmaxf(fmaxf(fabsf(v1.x), fabsf(v1.y)), fmaxf(fabsf(v1.z), fabsf(v1.w))));
    #pragma unroll
    for (int m = 1; m < 64; m <<= 1) {
        ss += __shfl_xor(ss, m);
        mx = fmaxf(mx, __shfl_xor(mx, m));
    }
    float nrm = fmaxf(sqrtf(ss), 1e-12f);
    float ma  = fmaxf(mx, 1e-20f);
    float qs  = 127.0f / ma;
    if (l == 0) (isw ? wsc : es)[row] = ma / (127.0f * nrm);
    char8 q;
    q[0]=(char)__float2int_rn(v0.x*qs); q[1]=(char)__float2int_rn(v0.y*qs);
    q[2]=(char)__float2int_rn(v0.z*qs); q[3]=(char)__float2int_rn(v0.w*qs);
    q[4]=(char)__float2int_rn(v1.x*qs); q[5]=(char)__float2int_rn(v1.y*qs);
    q[6]=(char)__float2int_rn(v1.z*qs); q[7]=(char)__float2int_rn(v1.w*qs);
    *reinterpret_cast<char8*>((isw ? wi8 : ei8) + (size_t)row * DD + l * 8) = q;
}

// ---------------- kernel 2: i8 GEMM, NO LDS, NO BARRIERS, B streamed to regs ----
// 1024 blocks (8 m-tiles x 128 splits), 256 thr = 4 waves; each wave owns
// 32 rows (af[2][8] = 64 VGPR, loaded once) and loops over ~12 col-tiles of 32.
// Per round: 16 global_load_dwordx4 (2 base ptrs + compile-time offsets) feed
// 32 MFMA i8; waves are fully unsynchronized -> loads of round i+1 overlap
// MFMAs of round i by register dependence alone (the m114 mechanism).
// The block's 4 wm-waves share B lines via L1. Epilogue exp2, rs in regs,
// one atomicAdd per row at the end.
__global__ __launch_bounds__(256, 4) void arc_gemm_i8_kernel(
        const char* __restrict__ ei8,    // [1024][512] i8
        const char* __restrict__ wi8,    // [50048][512] i8 (padded)
        const float* __restrict__ es,    // [1024]
        const float* __restrict__ wsc,   // [50048] (padded)
        float* __restrict__ rowsum)      // [1024]
{
    const int t   = threadIdx.x;       // 0..255
    const int wid = t >> 6;            // wave 0..3 (32-row chunk within m-tile)
    const int l   = t & 63;
    const int r16 = l & 15;
    const int kg  = l >> 4;

    // XCD-bijective: XCD k gets 16 splits x all 8 m-tiles (~3.3 MB W in its L2)
    const int bid  = blockIdx.x;
    const int bidp = (bid & 7) * 128 + (bid >> 3);
    const int mt = bidp & 7;           // m-tile 0..7
    const int s  = bidp >> 3;          // split 0..127
    const int rowb = mt * 128 + wid * 32;            // this wave's 32 rows
    const int nt0 = (s < 28) ? s * 13 : 12 * s + 28; // col-tiles (q=12, r=28)
    const int cnt = (s < 28) ? 13 : 12;

    // ---- A fragments: 2 m-frags x 8 kk, 16 B each -> 64 VGPR ----
    i32x4 af[2][8];
    #pragma unroll
    for (int fm = 0; fm < 2; ++fm)
        #pragma unroll
        for (int kk = 0; kk < 8; ++kk)
            af[fm][kk] = *reinterpret_cast<const i32x4*>(
                ei8 + (size_t)(rowb + fm * 16 + r16) * DD + kk * 64 + kg * 16);

    // ---- per-row e-scale hoist ----
    float se_r[2][4];
    #pragma unroll
    for (int fm = 0; fm < 2; ++fm)
        #pragma unroll
        for (int j = 0; j < 4; ++j)
            se_r[fm][j] = es[rowb + fm * 16 + kg * 4 + j];

    float rs[2][4];
    #pragma unroll
    for (int fm = 0; fm < 2; ++fm)
        #pragma unroll
        for (int j = 0; j < 4; ++j) rs[fm][j] = 0.f;

    // ---- per-lane B base pointers (advance 32 rows * 512 B = 16384 B/round) ----
    const char* pb0 = wi8 + (size_t)(nt0 * 32 + r16) * DD + kg * 16;
    const char* pb1 = pb0 + 16 * DD;
    const float* wp = wsc + nt0 * 32 + r16;

    for (int i = 0; i < cnt; ++i) {
        // folded coefficients: wsc * 64 * log2e
        float sw_0 = wp[0]  * SCALE_L2E_F;
        float sw_1 = wp[16] * SCALE_L2E_F;
        wp += 32;

        i32x4 acc[2][2];
        #pragma unroll
        for (int fm = 0; fm < 2; ++fm)
            #pragma unroll
            for (int fn = 0; fn < 2; ++fn) acc[fm][fn] = (i32x4){0, 0, 0, 0};

        #pragma unroll
        for (int kk = 0; kk < 8; ++kk) {
            i32x4 b0 = *reinterpret_cast<const i32x4*>(pb0 + kk * 64);
            i32x4 b1 = *reinterpret_cast<const i32x4*>(pb1 + kk * 64);
            acc[0][0] = __builtin_amdgcn_mfma_i32_16x16x64_i8(af[0][kk], b0, acc[0][0], 0, 0, 0);
            acc[1][0] = __builtin_amdgcn_mfma_i32_16x16x64_i8(af[1][kk], b0, acc[1][0], 0, 0, 0);
            acc[0][1] = __builtin_amdgcn_mfma_i32_16x16x64_i8(af[0][kk], b1, acc[0][1], 0, 0, 0);
            acc[1][1] = __builtin_amdgcn_mfma_i32_16x16x64_i8(af[1][kk], b1, acc[1][1], 0, 0, 0);
        }
        pb0 += 32 * DD;
        pb1 += 32 * DD;

        // ---- epilogue: rs += exp2(fma(d, se*sw, -64*log2e)), branch-free ----
        #pragma unroll
        for (int fm = 0; fm < 2; ++fm)
            #pragma unroll
            for (int j = 0; j < 4; ++j) {
                float k0 = se_r[fm][j] * sw_0;
                float k1 = se_r[fm][j] * sw_1;
                rs[fm][j] += exp2f(fmaf((float)acc[fm][0][j], k0, -SCALE_L2E_F));
                rs[fm][j] += exp2f(fmaf((float)acc[fm][1][j], k1, -SCALE_L2E_F));
            }
    }

    // ---- wave end: shfl-reduce over r16, one atomicAdd per row ----
    #pragma unroll
    for (int fm = 0; fm < 2; ++fm) {
        #pragma unroll
        for (int j = 0; j < 4; ++j) {
            float v = rs[fm][j];
            #pragma unroll
            for (int mk = 1; mk < 16; mk <<= 1) v += __shfl_xor(v, mk);
            if (r16 == 0) {
                int grow = rowb + fm * 16 + kg * 4 + j;
                atomicAdd(&rowsum[grow], v);
            }
        }
    }
}

// ---------------- kernel 3: finish = labfix + nll + mean (atomic) ----------------
__global__ void finish_kernel(const char* __restrict__ ei8, const char* __restrict__ wi8,
                              const float* __restrict__ es, const float* __restrict__ wsc,
                              const int* __restrict__ labels,
                              const float* __restrict__ rowsum, float* __restrict__ out) {
    const int b = blockIdx.x;          // 1024 blocks
    const int l = threadIdx.x;         // 64 threads
    const int lab = labels[b];
    char8 a = *reinterpret_cast<const char8*>(ei8 + (size_t)b * DD + l * 8);
    char8 w = *reinterpret_cast<const char8*>(wi8 + (size_t)lab * DD + l * 8);
    int d = 0;
    #pragma unroll
    for (int k = 0; k < 8; ++k) d += (int)a[k] * (int)w[k];
    #pragma unroll
    for (int m = 1; m < 64; m <<= 1) d += __shfl_xor(d, m);
    if (l == 0) {
        // bit-match the GEMM's unmargined term:
        //   sw = wsc*SCALE*log2e; k = es*sw; sub = exp2(fma(d, k, -SCALE*log2e))
        float swl = wsc[lab] * SCALE_L2E_F;
        float kf  = es[b] * swl;
        float sub = exp2f(fmaf((float)d, kf, -SCALE_L2E_F));
        float cosv = (float)d * es[b] * wsc[lab];
        float c2 = fminf(fmaxf(cosv * cosv, 0.f), 1.f);
        float phi = cosv * COS_M_F - sqrtf(1.f - c2) * SIN_M_F;
        phi = (cosv > TH_F) ? phi : (cosv - MM_F);
        float ml = SCALE_F * phi;
        float Sf = rowsum[b] + __expf(ml - SCALE_F) - sub;
        float nll = -(ml - SCALE_F - logf(Sf));
        atomicAdd(out, nll * (1.0f / BB));
    }
}

// ---------------- launcher ----------------
extern "C" void kernel_launch(void* const* d_in, const int* in_sizes, int n_in,
                              void* d_out, int out_size, void* d_ws, size_t ws_size,
                              hipStream_t stream) {
    const float* emb    = (const float*)d_in[0];
    const int*   labels = (const int*)d_in[1];
    const float* wgt    = (const float*)d_in[2];
    float* out = (float*)d_out;
    char* ws = (char*)d_ws;

    float* rowsum = (float*)(ws + OFF_RS);
    float* es     = (float*)(ws + OFF_ES);
    float* wsc    = (float*)(ws + OFF_WS);
    char*  ei8    = (char*)(ws + OFF_EI8);
    char*  wi8    = (char*)(ws + OFF_WI8);

    quant_kernel<<<12757, 256, 0, stream>>>(emb, wgt, ei8, es, wi8, wsc, rowsum, out);
    arc_gemm_i8_kernel<<<NBLK, 256, 0, stream>>>(ei8, wi8, es, wsc, rowsum);
    finish_kernel<<<BB, 64, 0, stream>>>(ei8, wi8, es, wsc, labels, rowsum, out);
}

// Round 15
// 77.870 us; speedup vs baseline: 1.8339x; 1.8339x over previous
//
#include <hip/hip_runtime.h>
#include <hip/hip_bf16.h>
#include <cstdint>

// ---------------- problem constants ----------------
#define BB 1024          // batch
#define DD 512           // dim
#define CC 50000         // classes
#define CCP 50048        // padded classes (782 * 64)
#define NTN 782          // n-tiles (BN=64)
#define NBLK 512         // 8 m-tiles * 64 n-splits = 2 blocks/CU exactly
#define SCALE_F 64.0f
#define COS_M_F 0.87758256189037276f
#define SIN_M_F 0.47942553860420301f
#define TH_F   (-0.87758256189037276f)
#define MM_F   0.23971276930210156f

typedef __attribute__((ext_vector_type(4))) int i32x4;
typedef __attribute__((ext_vector_type(8))) char char8;

// ---------------- ws layout (bytes) ----------------
#define OFF_RS   ((size_t)0)                          // [1024] float row sum-exp accum
#define OFF_ES   (OFF_RS + 4096)                      // [1024] float (e scales)
#define OFF_WS   (OFF_ES + 4096)                      // [50048] float (w scales, padded)
#define OFF_EI8  (OFF_WS + 204800)                    // [1024][512] i8
#define OFF_WI8  (OFF_EI8 + (size_t)BB*DD)            // [50048][512] i8 (padded)

// ---------------- kernel 1: fused normalize+quantize + init -------------------
__global__ void quant_kernel(const float* __restrict__ emb, const float* __restrict__ wgt,
                             char* __restrict__ ei8, float* __restrict__ es,
                             char* __restrict__ wi8, float* __restrict__ wsc,
                             float* __restrict__ rowsum, float* __restrict__ out) {
    const int blk = blockIdx.x;
    if (blk == 12756) {
        const int t = threadIdx.x;   // 256
        #pragma unroll
        for (int i = 0; i < 4; ++i) rowsum[i * 256 + t] = 0.f;
        if (t == 0) out[0] = 0.f;
        // zero pad rows 50000..50047 (24576 B): 96 B per thread
        int4* pz = reinterpret_cast<int4*>(wi8 + (size_t)CC * DD + t * 96);
        #pragma unroll
        for (int i = 0; i < 6; ++i) pz[i] = (int4){0, 0, 0, 0};
        if (t < CCP - CC) wsc[CC + t] = 0.f;
        return;
    }
    const int r4 = threadIdx.x >> 6;
    const int l  = threadIdx.x & 63;
    const bool isw = blk < 12500;
    const int row = isw ? (blk * 4 + r4) : ((blk - 12500) * 4 + r4);
    const float* src = (isw ? wgt : emb) + (size_t)row * DD;
    const float4* r = reinterpret_cast<const float4*>(src);
    float4 v0 = r[l * 2 + 0];
    float4 v1 = r[l * 2 + 1];
    float ss = v0.x*v0.x + v0.y*v0.y + v0.z*v0.z + v0.w*v0.w
             + v1.x*v1.x + v1.y*v1.y + v1.z*v1.z + v1.w*v1.w;
    float mx = fmaxf(fmaxf(fmaxf(fabsf(v0.x), fabsf(v0.y)), fmaxf(fabsf(v0.z), fabsf(v0.w))),
                     fmaxf(fmaxf(fabsf(v1.x), fabsf(v1.y)), fmaxf(fabsf(v1.z), fabsf(v1.w))));
    #pragma unroll
    for (int m = 1; m < 64; m <<= 1) {
        ss += __shfl_xor(ss, m);
        mx = fmaxf(mx, __shfl_xor(mx, m));
    }
    float nrm = fmaxf(sqrtf(ss), 1e-12f);
    float ma  = fmaxf(mx, 1e-20f);
    float qs  = 127.0f / ma;
    if (l == 0) (isw ? wsc : es)[row] = ma / (127.0f * nrm);
    char8 q;
    q[0]=(char)__float2int_rn(v0.x*qs); q[1]=(char)__float2int_rn(v0.y*qs);
    q[2]=(char)__float2int_rn(v0.z*qs); q[3]=(char)__float2int_rn(v0.w*qs);
    q[4]=(char)__float2int_rn(v1.x*qs); q[5]=(char)__float2int_rn(v1.y*qs);
    q[6]=(char)__float2int_rn(v1.z*qs); q[7]=(char)__float2int_rn(v1.w*qs);
    *reinterpret_cast<char8*>((isw ? wi8 : ei8) + (size_t)row * DD + l * 8) = q;
}

// ---------------- kernel 2: i8 GEMM (r10 base) + 2-deep B register prefetch ----
// 512 blocks (8 m-tiles x 64 splits), 512 thr = 8 waves (4m x 2n); wave 32x32.
// A: af[2][8]=64 VGPR loaded once. B: [4 kk2][64][128B] LDS, per-128B XOR
// swizzle, double-buffered 2x32 KB -> 2 blocks/CU, 4 waves/SIMD.
// CHANGE vs r10 (only): inner kk-loop software-pipelined in registers -- read
// B pair kk+1 BEFORE the 4 MFMAs of pair kk, so ds_read latency hides under
// the matrix pipe within each wave (+8 VGPR).
__global__ __launch_bounds__(512, 4) void arc_gemm_i8_kernel(
        const char* __restrict__ ei8,    // [1024][512] i8
        const char* __restrict__ wi8,    // [50048][512] i8 (padded)
        const float* __restrict__ es,    // [1024]
        const float* __restrict__ wsc,   // [50048] (padded)
        float* __restrict__ rowsum)      // [1024]
{
    __shared__ __align__(16) char lds[2][32768];

    const int t   = threadIdx.x;       // 0..511
    const int wid = t >> 6;
    const int wm  = wid >> 1;          // 0..3 (32-row chunk)
    const int wn  = wid & 1;           // 0..1 (32-col chunk)
    const int l   = t & 63;
    const int r16 = l & 15;
    const int kg  = l >> 4;

    // XCD-bijective: XCD k gets splits [8k,8k+8) x all 8 m-tiles.
    const int bid  = blockIdx.x;
    const int bidp = (bid & 7) * 64 + (bid >> 3);
    const int mt = bidp & 7;           // m-tile 0..7
    const int s  = bidp >> 3;          // split 0..63
    const int m0 = mt * 128;
    const int nt0 = (s < 14) ? s * 13 : 12 * s + 14;
    const int cnt = (s < 14) ? 13 : 12;

    // ---- A fragments: 2 m-frags x 8 kk, 16 B each -> 64 VGPR ----
    i32x4 af[2][8];
    #pragma unroll
    for (int fm = 0; fm < 2; ++fm)
        #pragma unroll
        for (int kk = 0; kk < 8; ++kk)
            af[fm][kk] = *reinterpret_cast<const i32x4*>(
                ei8 + (size_t)(m0 + wm * 32 + fm * 16 + r16) * DD + kk * 64 + kg * 16);

    // ---- per-row e-scale hoist ----
    float se_r[2][4];
    #pragma unroll
    for (int fm = 0; fm < 2; ++fm)
        #pragma unroll
        for (int j = 0; j < 4; ++j)
            se_r[fm][j] = es[m0 + wm * 32 + fm * 16 + kg * 4 + j];

    float rs[2][4];
    #pragma unroll
    for (int fm = 0; fm < 2; ++fm)
        #pragma unroll
        for (int j = 0; j < 4; ++j) rs[fm][j] = 0.f;

    // ---- persistent stage pointers (stride 64 rows * 512 B = 32768 B/round) ----
    const char* sp4[4];
    #pragma unroll
    for (int i = 0; i < 4; ++i) {
        int flat = (i * 512 + t) * 16;
        int kk2  = flat >> 13;
        int row  = (flat >> 7) & 63;
        int col  = flat & 127;
        int scol = col ^ ((row & 7) << 4);
        sp4[i] = wi8 + (size_t)(nt0 * 64 + row) * DD + kk2 * 128 + scol;
    }
    auto stageB = [&](int buf) {
        #pragma unroll
        for (int i = 0; i < 4; ++i) {
            __builtin_amdgcn_global_load_lds(
                (const __attribute__((address_space(1))) void*)sp4[i],
                (__attribute__((address_space(3))) void*)(&lds[buf][(i * 512 + t) * 16]),
                16, 0, 0);
            sp4[i] += 64 * DD;
        }
    };
    // w-scale pointer for this thread's two columns (stride 64 floats/round)
    const float* wp = wsc + nt0 * 64 + wn * 32 + r16;

    // B-read helper: compile-time (kk, fn) -> swizzled LDS offset
    const int brow0 = wn * 32 + r16;          // fn=0 row
    const int brow1 = wn * 32 + 16 + r16;     // fn=1 row

    // ---- prologue ----
    stageB(0);
    asm volatile("s_waitcnt vmcnt(0)" ::: "memory");
    __builtin_amdgcn_s_barrier();

    for (int i = 0; i < cnt; ++i) {
        const int buf = i & 1;
        if (i + 1 < cnt) stageB(buf ^ 1);

        // hoisted: per-col folded coefficients (latency hidden under MFMA)
        float sw64_0 = wp[0]  * SCALE_F;
        float sw64_1 = wp[16] * SCALE_F;
        wp += 64;

        // ---- compute: 8 kk, 2-deep register-pipelined B reads ----
        i32x4 acc[2][2];
        #pragma unroll
        for (int fm = 0; fm < 2; ++fm)
            #pragma unroll
            for (int fn = 0; fn < 2; ++fn) acc[fm][fn] = (i32x4){0, 0, 0, 0};

        auto rdB = [&](int kk, int row) -> i32x4 {
            int off = (kk >> 1) * 8192 + row * 128
                    + (((kk & 1) * 64 + kg * 16) ^ ((row & 7) << 4));
            return *reinterpret_cast<const i32x4*>(&lds[buf][off]);
        };

        i32x4 b0 = rdB(0, brow0);
        i32x4 b1 = rdB(0, brow1);
        #pragma unroll
        for (int kk = 0; kk < 8; ++kk) {
            i32x4 n0 = b0, n1 = b1;
            if (kk < 7) {                      // issue next pair before MFMAs
                n0 = rdB(kk + 1, brow0);
                n1 = rdB(kk + 1, brow1);
            }
            acc[0][0] = __builtin_amdgcn_mfma_i32_16x16x64_i8(af[0][kk], b0, acc[0][0], 0, 0, 0);
            acc[1][0] = __builtin_amdgcn_mfma_i32_16x16x64_i8(af[1][kk], b0, acc[1][0], 0, 0, 0);
            acc[0][1] = __builtin_amdgcn_mfma_i32_16x16x64_i8(af[0][kk], b1, acc[0][1], 0, 0, 0);
            acc[1][1] = __builtin_amdgcn_mfma_i32_16x16x64_i8(af[1][kk], b1, acc[1][1], 0, 0, 0);
            b0 = n0; b1 = n1;
        }

        // ---- epilogue: rs += exp(fma(d, se*sw*64, -64)), branch-free ----
        #pragma unroll
        for (int fm = 0; fm < 2; ++fm)
            #pragma unroll
            for (int j = 0; j < 4; ++j) {
                float k0 = se_r[fm][j] * sw64_0;
                float k1 = se_r[fm][j] * sw64_1;
                rs[fm][j] += __expf(fmaf((float)acc[fm][0][j], k0, -SCALE_F));
                rs[fm][j] += __expf(fmaf((float)acc[fm][1][j], k1, -SCALE_F));
            }

        asm volatile("s_waitcnt vmcnt(0)" ::: "memory");
        __builtin_amdgcn_s_barrier();
    }

    // ---- block end: shfl-reduce over r16, one atomicAdd per row per wave ----
    #pragma unroll
    for (int fm = 0; fm < 2; ++fm) {
        #pragma unroll
        for (int j = 0; j < 4; ++j) {
            float v = rs[fm][j];
            #pragma unroll
            for (int mk = 1; mk < 16; mk <<= 1) v += __shfl_xor(v, mk);
            if (r16 == 0) {
                int grow = m0 + wm * 32 + fm * 16 + kg * 4 + j;
                atomicAdd(&rowsum[grow], v);
            }
        }
    }
}

// ---------------- kernel 3: finish = labfix + nll + mean (atomic) ----------------
__global__ void finish_kernel(const char* __restrict__ ei8, const char* __restrict__ wi8,
                              const float* __restrict__ es, const float* __restrict__ wsc,
                              const int* __restrict__ labels,
                              const float* __restrict__ rowsum, float* __restrict__ out) {
    const int b = blockIdx.x;          // 1024 blocks
    const int l = threadIdx.x;         // 64 threads
    const int lab = labels[b];
    char8 a = *reinterpret_cast<const char8*>(ei8 + (size_t)b * DD + l * 8);
    char8 w = *reinterpret_cast<const char8*>(wi8 + (size_t)lab * DD + l * 8);
    int d = 0;
    #pragma unroll
    for (int k = 0; k < 8; ++k) d += (int)a[k] * (int)w[k];
    #pragma unroll
    for (int m = 1; m < 64; m <<= 1) d += __shfl_xor(d, m);
    if (l == 0) {
        // bit-match the GEMM's unmargined term: exp(fma(d, es*(wsc*64), -64))
        float kf  = es[b] * (wsc[lab] * SCALE_F);
        float sub = __expf(fmaf((float)d, kf, -SCALE_F));
        float cosv = (float)d * es[b] * wsc[lab];
        float c2 = fminf(fmaxf(cosv * cosv, 0.f), 1.f);
        float phi = cosv * COS_M_F - sqrtf(1.f - c2) * SIN_M_F;
        phi = (cosv > TH_F) ? phi : (cosv - MM_F);
        float ml = SCALE_F * phi;
        float Sf = rowsum[b] + __expf(ml - SCALE_F) - sub;
        float nll = -(ml - SCALE_F - logf(Sf));
        atomicAdd(out, nll * (1.0f / BB));
    }
}

// ---------------- launcher ----------------
extern "C" void kernel_launch(void* const* d_in, const int* in_sizes, int n_in,
                              void* d_out, int out_size, void* d_ws, size_t ws_size,
                              hipStream_t stream) {
    const float* emb    = (const float*)d_in[0];
    const int*   labels = (const int*)d_in[1];
    const float* wgt    = (const float*)d_in[2];
    float* out = (float*)d_out;
    char* ws = (char*)d_ws;

    float* rowsum = (float*)(ws + OFF_RS);
    float* es     = (float*)(ws + OFF_ES);
    float* wsc    = (float*)(ws + OFF_WS);
    char*  ei8    = (char*)(ws + OFF_EI8);
    char*  wi8    = (char*)(ws + OFF_WI8);

    quant_kernel<<<12757, 256, 0, stream>>>(emb, wgt, ei8, es, wi8, wsc, rowsum, out);
    arc_gemm_i8_kernel<<<NBLK, 512, 0, stream>>>(ei8, wi8, es, wsc, rowsum);
    finish_kernel<<<BB, 64, 0, stream>>>(ei8, wi8, es, wsc, labels, rowsum, out);
}

// Round 16
// 76.542 us; speedup vs baseline: 1.8657x; 1.0174x over previous
//
#include <hip/hip_runtime.h>
#include <hip/hip_bf16.h>
#include <cstdint>

// ---------------- problem constants ----------------
#define BB 1024          // batch
#define DD 512           // dim
#define CC 50000         // classes
#define CCP 50048        // padded classes (782 * 64)
#define NTN 782          // n-tiles (BN=64)
#define NBLK 512         // 8 m-tiles * 64 n-splits = 2 blocks/CU exactly
#define SCALE_F 64.0f
#define COS_M_F 0.87758256189037276f
#define SIN_M_F 0.47942553860420301f
#define TH_F   (-0.87758256189037276f)
#define MM_F   0.23971276930210156f

typedef __attribute__((ext_vector_type(4))) int i32x4;
typedef __attribute__((ext_vector_type(8))) char char8;

// ---------------- ws layout (bytes) ----------------
#define OFF_RS   ((size_t)0)                          // [1024] float row sum-exp accum
#define OFF_ES   (OFF_RS + 4096)                      // [1024] float (e scales)
#define OFF_WS   (OFF_ES + 4096)                      // [50048] float (w scales, padded)
#define OFF_EI8  (OFF_WS + 204800)                    // [1024][512] i8
#define OFF_WI8  (OFF_EI8 + (size_t)BB*DD)            // [50048][512] i8 (padded)

// ---------------- kernel 1: fused normalize+quantize + init -------------------
__global__ void quant_kernel(const float* __restrict__ emb, const float* __restrict__ wgt,
                             char* __restrict__ ei8, float* __restrict__ es,
                             char* __restrict__ wi8, float* __restrict__ wsc,
                             float* __restrict__ rowsum, float* __restrict__ out) {
    const int blk = blockIdx.x;
    if (blk == 12756) {
        const int t = threadIdx.x;   // 256
        #pragma unroll
        for (int i = 0; i < 4; ++i) rowsum[i * 256 + t] = 0.f;
        if (t == 0) out[0] = 0.f;
        // zero pad rows 50000..50047 (24576 B): 96 B per thread
        int4* pz = reinterpret_cast<int4*>(wi8 + (size_t)CC * DD + t * 96);
        #pragma unroll
        for (int i = 0; i < 6; ++i) pz[i] = (int4){0, 0, 0, 0};
        if (t < CCP - CC) wsc[CC + t] = 0.f;
        return;
    }
    const int r4 = threadIdx.x >> 6;
    const int l  = threadIdx.x & 63;
    const bool isw = blk < 12500;
    const int row = isw ? (blk * 4 + r4) : ((blk - 12500) * 4 + r4);
    const float* src = (isw ? wgt : emb) + (size_t)row * DD;
    const float4* r = reinterpret_cast<const float4*>(src);
    float4 v0 = r[l * 2 + 0];
    float4 v1 = r[l * 2 + 1];
    float ss = v0.x*v0.x + v0.y*v0.y + v0.z*v0.z + v0.w*v0.w
             + v1.x*v1.x + v1.y*v1.y + v1.z*v1.z + v1.w*v1.w;
    float mx = fmaxf(fmaxf(fmaxf(fabsf(v0.x), fabsf(v0.y)), fmaxf(fabsf(v0.z), fabsf(v0.w))),
                     fmaxf(fmaxf(fabsf(v1.x), fabsf(v1.y)), fmaxf(fabsf(v1.z), fabsf(v1.w))));
    #pragma unroll
    for (int m = 1; m < 64; m <<= 1) {
        ss += __shfl_xor(ss, m);
        mx = fmaxf(mx, __shfl_xor(mx, m));
    }
    float nrm = fmaxf(sqrtf(ss), 1e-12f);
    float ma  = fmaxf(mx, 1e-20f);
    float qs  = 127.0f / ma;
    if (l == 0) (isw ? wsc : es)[row] = ma / (127.0f * nrm);
    char8 q;
    q[0]=(char)__float2int_rn(v0.x*qs); q[1]=(char)__float2int_rn(v0.y*qs);
    q[2]=(char)__float2int_rn(v0.z*qs); q[3]=(char)__float2int_rn(v0.w*qs);
    q[4]=(char)__float2int_rn(v1.x*qs); q[5]=(char)__float2int_rn(v1.y*qs);
    q[6]=(char)__float2int_rn(v1.z*qs); q[7]=(char)__float2int_rn(v1.w*qs);
    *reinterpret_cast<char8*>((isw ? wi8 : ei8) + (size_t)row * DD + l * 8) = q;
}

// ---------------- kernel 2: i8 GEMM, A-in-regs, persistent n-loop, atomic out ----
// 512 blocks (8 m-tiles x 64 splits), 512 threads = 8 waves (4m x 2n);
// wave tile 32 rows x 32 cols. A: af[2][8]=64 VGPR loaded once. B: whole-K
// [4 kk2][64 rows][128B] LDS, per-128B XOR swizzle, double-buffered 64 KB.
// W padded to 50048 rows -> no clamps, branch-free epilogue with folded
// exp coefficient; stage pointers increment by constant 32 KB per round.
__global__ __launch_bounds__(512, 4) void arc_gemm_i8_kernel(
        const char* __restrict__ ei8,    // [1024][512] i8
        const char* __restrict__ wi8,    // [50048][512] i8 (padded)
        const float* __restrict__ es,    // [1024]
        const float* __restrict__ wsc,   // [50048] (padded)
        float* __restrict__ rowsum)      // [1024]
{
    __shared__ __align__(16) char lds[2][32768];

    const int t   = threadIdx.x;       // 0..511
    const int wid = t >> 6;
    const int wm  = wid >> 1;          // 0..3 (32-row chunk)
    const int wn  = wid & 1;           // 0..1 (32-col chunk)
    const int l   = t & 63;
    const int r16 = l & 15;
    const int kg  = l >> 4;

    // XCD-bijective: XCD k gets splits [8k,8k+8) x all 8 m-tiles.
    const int bid  = blockIdx.x;
    const int bidp = (bid & 7) * 64 + (bid >> 3);
    const int mt = bidp & 7;           // m-tile 0..7
    const int s  = bidp >> 3;          // split 0..63
    const int m0 = mt * 128;
    const int nt0 = (s < 14) ? s * 13 : 12 * s + 14;
    const int cnt = (s < 14) ? 13 : 12;

    // ---- A fragments: 2 m-frags x 8 kk, 16 B each -> 64 VGPR ----
    i32x4 af[2][8];
    #pragma unroll
    for (int fm = 0; fm < 2; ++fm)
        #pragma unroll
        for (int kk = 0; kk < 8; ++kk)
            af[fm][kk] = *reinterpret_cast<const i32x4*>(
                ei8 + (size_t)(m0 + wm * 32 + fm * 16 + r16) * DD + kk * 64 + kg * 16);

    // ---- per-row e-scale hoist ----
    float se_r[2][4];
    #pragma unroll
    for (int fm = 0; fm < 2; ++fm)
        #pragma unroll
        for (int j = 0; j < 4; ++j)
            se_r[fm][j] = es[m0 + wm * 32 + fm * 16 + kg * 4 + j];

    float rs[2][4];
    #pragma unroll
    for (int fm = 0; fm < 2; ++fm)
        #pragma unroll
        for (int j = 0; j < 4; ++j) rs[fm][j] = 0.f;

    // ---- persistent stage pointers (stride 64 rows * 512 B = 32768 B/round) ----
    const char* sp4[4];
    #pragma unroll
    for (int i = 0; i < 4; ++i) {
        int flat = (i * 512 + t) * 16;
        int kk2  = flat >> 13;
        int row  = (flat >> 7) & 63;
        int col  = flat & 127;
        int scol = col ^ ((row & 7) << 4);
        sp4[i] = wi8 + (size_t)(nt0 * 64 + row) * DD + kk2 * 128 + scol;
    }
    auto stageB = [&](int buf) {
        #pragma unroll
        for (int i = 0; i < 4; ++i) {
            __builtin_amdgcn_global_load_lds(
                (const __attribute__((address_space(1))) void*)sp4[i],
                (__attribute__((address_space(3))) void*)(&lds[buf][(i * 512 + t) * 16]),
                16, 0, 0);
            sp4[i] += 64 * DD;
        }
    };
    // w-scale pointer for this thread's two columns (stride 64 floats/round)
    const float* wp = wsc + nt0 * 64 + wn * 32 + r16;

    // ---- prologue ----
    stageB(0);
    asm volatile("s_waitcnt vmcnt(0)" ::: "memory");
    __builtin_amdgcn_s_barrier();

    for (int i = 0; i < cnt; ++i) {
        const int buf = i & 1;
        if (i + 1 < cnt) stageB(buf ^ 1);

        // hoisted: per-col folded coefficients (latency hidden under MFMA)
        float sw64_0 = wp[0]  * SCALE_F;
        float sw64_1 = wp[16] * SCALE_F;
        wp += 64;

        // ---- compute: 8 kk, B from LDS, A from regs ----
        i32x4 acc[2][2];
        #pragma unroll
        for (int fm = 0; fm < 2; ++fm)
            #pragma unroll
            for (int fn = 0; fn < 2; ++fn) acc[fm][fn] = (i32x4){0, 0, 0, 0};
        #pragma unroll
        for (int kk = 0; kk < 8; ++kk) {
            i32x4 b[2];
            #pragma unroll
            for (int fn = 0; fn < 2; ++fn) {
                int row = wn * 32 + fn * 16 + r16;
                int off = (kk >> 1) * 8192 + row * 128
                        + (((kk & 1) * 64 + kg * 16) ^ ((row & 7) << 4));
                b[fn] = *reinterpret_cast<const i32x4*>(&lds[buf][off]);
            }
            #pragma unroll
            for (int fm = 0; fm < 2; ++fm)
                #pragma unroll
                for (int fn = 0; fn < 2; ++fn)
                    acc[fm][fn] = __builtin_amdgcn_mfma_i32_16x16x64_i8(af[fm][kk], b[fn], acc[fm][fn], 0, 0, 0);
        }

        // ---- epilogue: rs += exp(fma(d, se*sw*64, -64)), branch-free ----
        #pragma unroll
        for (int fm = 0; fm < 2; ++fm)
            #pragma unroll
            for (int j = 0; j < 4; ++j) {
                float k0 = se_r[fm][j] * sw64_0;
                float k1 = se_r[fm][j] * sw64_1;
                rs[fm][j] += __expf(fmaf((float)acc[fm][0][j], k0, -SCALE_F));
                rs[fm][j] += __expf(fmaf((float)acc[fm][1][j], k1, -SCALE_F));
            }

        asm volatile("s_waitcnt vmcnt(0)" ::: "memory");
        __builtin_amdgcn_s_barrier();
    }

    // ---- block end: shfl-reduce over r16, one atomicAdd per row per wave ----
    #pragma unroll
    for (int fm = 0; fm < 2; ++fm) {
        #pragma unroll
        for (int j = 0; j < 4; ++j) {
            float v = rs[fm][j];
            #pragma unroll
            for (int mk = 1; mk < 16; mk <<= 1) v += __shfl_xor(v, mk);
            if (r16 == 0) {
                int grow = m0 + wm * 32 + fm * 16 + kg * 4 + j;
                atomicAdd(&rowsum[grow], v);
            }
        }
    }
}

// ---------------- kernel 3: finish = labfix + nll + mean (atomic) ----------------
__global__ void finish_kernel(const char* __restrict__ ei8, const char* __restrict__ wi8,
                              const float* __restrict__ es, const float* __restrict__ wsc,
                              const int* __restrict__ labels,
                              const float* __restrict__ rowsum, float* __restrict__ out) {
    const int b = blockIdx.x;          // 1024 blocks
    const int l = threadIdx.x;         // 64 threads
    const int lab = labels[b];
    char8 a = *reinterpret_cast<const char8*>(ei8 + (size_t)b * DD + l * 8);
    char8 w = *reinterpret_cast<const char8*>(wi8 + (size_t)lab * DD + l * 8);
    int d = 0;
    #pragma unroll
    for (int k = 0; k < 8; ++k) d += (int)a[k] * (int)w[k];
    #pragma unroll
    for (int m = 1; m < 64; m <<= 1) d += __shfl_xor(d, m);
    if (l == 0) {
        // bit-match the GEMM's unmargined term: exp(fma(d, es*(wsc*64), -64))
        float kf  = es[b] * (wsc[lab] * SCALE_F);
        float sub = __expf(fmaf((float)d, kf, -SCALE_F));
        float cosv = (float)d * es[b] * wsc[lab];
        float c2 = fminf(fmaxf(cosv * cosv, 0.f), 1.f);
        float phi = cosv * COS_M_F - sqrtf(1.f - c2) * SIN_M_F;
        phi = (cosv > TH_F) ? phi : (cosv - MM_F);
        float ml = SCALE_F * phi;
        float Sf = rowsum[b] + __expf(ml - SCALE_F) - sub;
        float nll = -(ml - SCALE_F - logf(Sf));
        atomicAdd(out, nll * (1.0f / BB));
    }
}

// ---------------- launcher ----------------
extern "C" void kernel_launch(void* const* d_in, const int* in_sizes, int n_in,
                              void* d_out, int out_size, void* d_ws, size_t ws_size,
                              hipStream_t stream) {
    const float* emb    = (const float*)d_in[0];
    const int*   labels = (const int*)d_in[1];
    const float* wgt    = (const float*)d_in[2];
    float* out = (float*)d_out;
    char* ws = (char*)d_ws;

    float* rowsum = (float*)(ws + OFF_RS);
    float* es     = (float*)(ws + OFF_ES);
    float* wsc    = (float*)(ws + OFF_WS);
    char*  ei8    = (char*)(ws + OFF_EI8);
    char*  wi8    = (char*)(ws + OFF_WI8);

    quant_kernel<<<12757, 256, 0, stream>>>(emb, wgt, ei8, es, wi8, wsc, rowsum, out);
    arc_gemm_i8_kernel<<<NBLK, 512, 0, stream>>>(ei8, wi8, es, wsc, rowsum);
    finish_kernel<<<BB, 64, 0, stream>>>(ei8, wi8, es, wsc, labels, rowsum, out);
}